// Round 13
// baseline (204.298 us; speedup 1.0000x reference)
//
#include <hip/hip_runtime.h>
#include <stdint.h>

// ---------------------------------------------------------------------------
// NestedSwiGLUMLP: out = (silu(g)*u*mask) @ w2[:, :Hh]^T + b2,  z = x@w1^T + b1
// B=8 S=4096 D=1024 H=2048 Hh=1024 E=4, tokens M=32768
// R13: revert to xs/bf16 gemm1 (R12's fp32-A path had 7.9M bank conflicts,
//      unexplained — abandoned). gemm1 widened: 512 thr / 8 waves (2m x 4n),
//      tile 128 rows x 128 gate-pairs (B = 256 rows, 48KB LDS). Per-wave
//      shape identical to proven R9 (64 acc regs, same swizzled reads, 0
//      conflicts) but 2x barrier amortization and +33% compute/staged-byte.
//      xconv restored; gemm2 = R9's 8-phase kernel8 (best measured).
// ws: a(64MB) | w1b(4MB) | w2b(2MB) | xs(64MB) | perm | em_sorted | hist | off
// ---------------------------------------------------------------------------

typedef __attribute__((ext_vector_type(8))) __bf16 bf16x8;
typedef __attribute__((ext_vector_type(4))) float f32x4;

#define MFMA16(a, b, c) __builtin_amdgcn_mfma_f32_16x16x32_bf16(a, b, c, 0, 0, 0)

#define BAR() asm volatile("s_barrier" ::: "memory")
#define VMCNT(n) asm volatile("s_waitcnt vmcnt(" #n ")" ::: "memory")

static __device__ __forceinline__ unsigned short f2bf(float f) {
  union { float f; uint32_t u; } v; v.f = f;
  uint32_t r = v.u + 0x7FFFu + ((v.u >> 16) & 1u);   // RNE
  return (unsigned short)(r >> 16);
}

static __device__ __forceinline__ void gload_lds16(const void* g, void* l) {
  __builtin_amdgcn_global_load_lds(
      (const __attribute__((address_space(1))) void*)g,
      (__attribute__((address_space(3))) void*)l, 16, 0, 0);
}

// ------------------------- weight cast (merged) -----------------------------
__global__ void conv_w_kernel(const float* __restrict__ w1,
                              const float* __restrict__ w2,
                              unsigned short* __restrict__ w1b,
                              unsigned short* __restrict__ w2b) {
  int bid = blockIdx.x;
  if (bid < 2048) {                                  // w1: 524288 float4s
    int i = bid * 256 + threadIdx.x;
    float4 v = ((const float4*)w1)[i];
    ushort4 o; o.x = f2bf(v.x); o.y = f2bf(v.y); o.z = f2bf(v.z); o.w = f2bf(v.w);
    ((ushort4*)w1b)[i] = o;
  } else {                                           // w2[:, :1024]
    int i = (bid - 2048) * 256 + threadIdx.x;
    int d = i >> 8;
    int h4 = (i & 255) * 4;
    float4 v = *(const float4*)(w2 + (size_t)d * 2048 + h4);
    ushort4 o; o.x = f2bf(v.x); o.y = f2bf(v.y); o.z = f2bf(v.z); o.w = f2bf(v.w);
    *(ushort4*)(w2b + (size_t)d * 1024 + h4) = o;
  }
}

// ------------------------- sort kernels (deterministic) ---------------------
__global__ void hist_kernel(const int* __restrict__ emask, int* __restrict__ hist) {
  __shared__ int h[4];
  int tid = threadIdx.x;
  if (tid < 4) h[tid] = 0;
  __syncthreads();
  int e = emask[blockIdx.x * 128 + tid];
  atomicAdd(&h[e], 1);
  __syncthreads();
  if (tid < 4) hist[blockIdx.x * 4 + tid] = h[tid];
}

__global__ void scan_kernel(const int* __restrict__ hist, int* __restrict__ off) {
  __shared__ int total[4];
  int tid = threadIdx.x;
  if (tid < 4) {
    int s = 0;
    for (int b = 0; b < 256; ++b) s += hist[b * 4 + tid];
    total[tid] = s;
  }
  __syncthreads();
  if (tid < 4) {
    int base = 0;
    for (int j = 0; j < tid; ++j) base += total[j];
    int run = base;
    for (int b = 0; b < 256; ++b) {
      off[b * 4 + tid] = run;
      run += hist[b * 4 + tid];
    }
  }
}

__global__ void scatter_kernel(const int* __restrict__ emask,
                               const int* __restrict__ off,
                               int* __restrict__ perm, int* __restrict__ em_sorted) {
  __shared__ int c0[4];
  int tid = threadIdx.x;
  int lane = tid & 63, wid = tid >> 6;
  int t = blockIdx.x * 128 + tid;
  int e = emask[t];
  unsigned long long b0 = __ballot(e == 0);
  unsigned long long b1 = __ballot(e == 1);
  unsigned long long b2 = __ballot(e == 2);
  unsigned long long b3 = __ballot(e == 3);
  if (tid == 0) {
    c0[0] = __popcll(b0); c0[1] = __popcll(b1);
    c0[2] = __popcll(b2); c0[3] = __popcll(b3);
  }
  __syncthreads();
  unsigned long long mine = (e == 0) ? b0 : (e == 1) ? b1 : (e == 2) ? b2 : b3;
  int rank = __popcll(mine & ((1ull << lane) - 1ull));
  if (wid) rank += c0[e];
  int pos = off[blockIdx.x * 4 + e] + rank;
  perm[pos] = t;
  em_sorted[pos] = e;
}

// ------------- x -> bf16, gathered into sorted order ------------------------
__global__ void xconv_kernel(const float* __restrict__ x, const int* __restrict__ perm,
                             unsigned short* __restrict__ xs) {
  int gid = blockIdx.x * 256 + threadIdx.x;
  int s = gid >> 7;
  int seg = gid & 127;
  int tok = perm[s];
  const float* src = x + (size_t)tok * 1024 + seg * 8;
  float4 v0 = *(const float4*)(src);
  float4 v1 = *(const float4*)(src + 4);
  bf16x8 hv;
  hv[0] = (__bf16)v0.x; hv[1] = (__bf16)v0.y; hv[2] = (__bf16)v0.z; hv[3] = (__bf16)v0.w;
  hv[4] = (__bf16)v1.x; hv[5] = (__bf16)v1.y; hv[6] = (__bf16)v1.z; hv[7] = (__bf16)v1.w;
  *(bf16x8*)(xs + (size_t)s * 1024 + seg * 8) = hv;
}

// --------- GEMM1: 512thr, 128 rows x 128 gate-pairs, 2-phase, swiglu --------
// grid (256, 8): x -> m-group (reversed: heavy first; XCD = x%8), y = 128-col
__global__ __launch_bounds__(512, 2)
void gemm1_sorted_kernel(const unsigned short* __restrict__ xs,
                         const int* __restrict__ em_sorted,
                         const unsigned short* __restrict__ w1b,
                         const float* __restrict__ b1,
                         unsigned short* __restrict__ a_out) {
  __shared__ __align__(16) char lds[49152];
  __shared__ int sred[8];
  char* AS = lds;             // 16384 B: 128 rows x 128B, swizzled
  char* BS = lds + 16384;     // 32768 B: gate rows 0..127, up rows 128..255

  const int tid = threadIdx.x;
  const int lane = tid & 63;
  const int w = tid >> 6;        // 0..7
  const int wm = w >> 2;         // 0/1: 64-row half
  const int wn = w & 3;          // 0..3: 32-pair quarter
  const int m0 = (255 - blockIdx.x) * 128;     // heavy groups dispatch first
  const int n0 = blockIdx.y * 128;             // gate cols n0..n0+127

  // block max expert over rows m0..m0+127
  int v = em_sorted[m0 + (tid & 127)];
  #pragma unroll
  for (int o = 32; o; o >>= 1) v = max(v, __shfl_xor(v, o));
  if (lane == 0) sred[w] = v;
  __syncthreads();
  int maxe = sred[0];
  #pragma unroll
  for (int i = 1; i < 8; ++i) maxe = max(maxe, sred[i]);
  if (n0 >= (128 << maxe)) return;      // whole tile inactive for this group

  f32x4 accg[4][2] = {};
  f32x4 accu[4][2] = {};

  for (int k0 = 0; k0 < 1024; k0 += 64) {
    // --- A tile (xs, sorted, linear rows): 2 gloads/thread ---
    #pragma unroll
    for (int i = 0; i < 2; ++i) {
      int c = (w * 2 + i) * 64 + lane;        // chunk id in [0,1024)
      int p = c * 16;
      int r = p >> 7;                         // 0..127
      int kb16 = ((p >> 4) & 7) ^ (r & 7);
      gload_lds16((const char*)xs + (((size_t)(m0 + r) * 1024 + k0) * 2) + kb16 * 16,
                  AS + (w * 2 + i) * 1024);
    }
    // --- B tile (w1b): gate rows then up rows, 4 gloads/thread ---
    #pragma unroll
    for (int i = 0; i < 4; ++i) {
      int c = (w * 4 + i) * 64 + lane;        // chunk id in [0,2048)
      int p = c * 16;
      int r = p >> 7;                         // 0..255
      int kb16 = ((p >> 4) & 7) ^ (r & 7);
      int h = (r < 128) ? (n0 + r) : (1024 + n0 + (r - 128));
      gload_lds16((const char*)w1b + (((size_t)h * 1024 + k0) * 2) + kb16 * 16,
                  BS + (w * 4 + i) * 1024);
    }
    __syncthreads();
    #pragma unroll
    for (int kk = 0; kk < 2; ++kk) {
      const int kbyte = kk * 64 + (lane >> 4) * 16;
      bf16x8 af[4], bg[2], bu[2];
      #pragma unroll
      for (int m = 0; m < 4; ++m) {
        int r = wm * 64 + m * 16 + (lane & 15);
        int o = (r * 128 + kbyte) ^ ((r & 7) << 4);
        af[m] = *(const bf16x8*)(AS + o);
      }
      #pragma unroll
      for (int n = 0; n < 2; ++n) {
        int j = wn * 32 + n * 16 + (lane & 15);   // gate col - n0
        int o = (j * 128 + kbyte) ^ ((j & 7) << 4);
        bg[n] = *(const bf16x8*)(BS + o);
        bu[n] = *(const bf16x8*)(BS + 16384 + o);
      }
      #pragma unroll
      for (int m = 0; m < 4; ++m)
        #pragma unroll
        for (int n = 0; n < 2; ++n) {
          accg[m][n] = MFMA16(af[m], bg[n], accg[m][n]);
          accu[m][n] = MFMA16(af[m], bu[n], accu[m][n]);
        }
    }
    __syncthreads();
  }
  // epilogue: a = silu(g + b1g) * (u + b1u) * (col < 128<<e)
  #pragma unroll
  for (int m = 0; m < 4; ++m) {
    int rbase = m0 + wm * 64 + m * 16 + (lane >> 4) * 4;
    int act[4];
    #pragma unroll
    for (int r = 0; r < 4; ++r) act[r] = 128 << em_sorted[rbase + r];
    #pragma unroll
    for (int n = 0; n < 2; ++n) {
      int col = n0 + wn * 32 + n * 16 + (lane & 15);
      float b1g = b1[col], b1u = b1[col + 1024];
      #pragma unroll
      for (int r = 0; r < 4; ++r) {
        float g = accg[m][n][r] + b1g;
        float u = accu[m][n][r] + b1u;
        float s = g / (1.f + __expf(-g));
        float val = (col < act[r]) ? (s * u) : 0.f;
        a_out[(size_t)(rbase + r) * 1024 + col] = f2bf(val);
      }
    }
  }
}

// ======================= 8-phase 256x256 GEMM machinery (gemm2) =============
static __device__ __forceinline__ void ds_loadA(const char* Abase, int lane,
                                                bf16x8 (&af)[4][2], int mh) {
  #pragma unroll
  for (int mf = 0; mf < 4; ++mf)
    #pragma unroll
    for (int kk = 0; kk < 2; ++kk) {
      int r = mh * 64 + mf * 16 + (lane & 15);
      int o = (r * 128 + kk * 64 + ((lane >> 4) * 16)) ^ ((r & 7) << 4);
      af[mf][kk] = *(const bf16x8*)(Abase + o);
    }
}

static __device__ __forceinline__ void ds_loadB(const char* Bbase, int lane, int wc,
                                                bf16x8 (&bf)[2][2], int nh) {
  #pragma unroll
  for (int nl = 0; nl < 2; ++nl)
    #pragma unroll
    for (int kk = 0; kk < 2; ++kk) {
      int n = nh * 2 + nl;
      int r = (wc & 1) * 64 + n * 16 + (lane & 15);
      int o = (r * 128 + kk * 64 + ((lane >> 4) * 16)) ^ ((r & 7) << 4);
      bf[nl][kk] = *(const bf16x8*)(Bbase + o);
    }
}

static __device__ __forceinline__ void mfma_quad(bf16x8 (&af)[4][2], bf16x8 (&bf)[2][2],
                                                 f32x4 (&acc)[8][4], int mh, int nh) {
  __builtin_amdgcn_s_setprio(1);
  #pragma unroll
  for (int mf = 0; mf < 4; ++mf)
    #pragma unroll
    for (int nl = 0; nl < 2; ++nl)
      #pragma unroll
      for (int kk = 0; kk < 2; ++kk)
        acc[mh * 4 + mf][nh * 2 + nl] =
            MFMA16(af[mf][kk], bf[nl][kk], acc[mh * 4 + mf][nh * 2 + nl]);
  __builtin_amdgcn_s_setprio(0);
}

template <class ST>
static __device__ __forceinline__ void kpair_steady(const ST& st, char* lds, int j,
    int lane, int wr, int wc, bf16x8 (&af)[4][2], bf16x8 (&bf0)[2][2],
    bf16x8 (&bf1)[2][2], f32x4 (&acc)[8][4]) {
  const int a = 2 * j, b = 2 * j + 1;
  const char* Aa = lds + (a & 1) * 32768 + wr * 16384;
  const char* Ab = lds + (b & 1) * 32768 + wr * 16384;
  const char* Ba = lds + 65536 + (a & 1) * 32768 + (wc >> 1) * 16384;
  const char* Bb = lds + 65536 + (b & 1) * 32768 + (wc >> 1) * 16384;
  ds_loadA(Aa, lane, af, 0); ds_loadB(Ba, lane, wc, bf0, 0);
  st.stageA(b, 0);            BAR(); mfma_quad(af, bf0, acc, 0, 0); BAR();
  ds_loadB(Ba, lane, wc, bf1, 1);
  st.stageA(b, 1);            BAR(); mfma_quad(af, bf1, acc, 0, 1); BAR();
  ds_loadA(Aa, lane, af, 1);
  st.stageB(a + 2, 0);        BAR(); mfma_quad(af, bf0, acc, 1, 0); BAR();
  st.stageB(a + 2, 1); VMCNT(4); BAR(); mfma_quad(af, bf1, acc, 1, 1); BAR();
  ds_loadA(Ab, lane, af, 0); ds_loadB(Bb, lane, wc, bf0, 0);
  st.stageA(a + 2, 0);        BAR(); mfma_quad(af, bf0, acc, 0, 0); BAR();
  ds_loadB(Bb, lane, wc, bf1, 1);
  st.stageA(a + 2, 1);        BAR(); mfma_quad(af, bf1, acc, 0, 1); BAR();
  ds_loadA(Ab, lane, af, 1);
  st.stageB(b + 2, 0);        BAR(); mfma_quad(af, bf0, acc, 1, 0); BAR();
  st.stageB(b + 2, 1); VMCNT(4); BAR(); mfma_quad(af, bf1, acc, 1, 1); BAR();
}

template <class ST>
static __device__ __forceinline__ void kpair_last(const ST& st, char* lds, int j,
    int lane, int wr, int wc, bf16x8 (&af)[4][2], bf16x8 (&bf0)[2][2],
    bf16x8 (&bf1)[2][2], f32x4 (&acc)[8][4]) {
  const int a = 2 * j, b = 2 * j + 1;
  const char* Aa = lds + (a & 1) * 32768 + wr * 16384;
  const char* Ab = lds + (b & 1) * 32768 + wr * 16384;
  const char* Ba = lds + 65536 + (a & 1) * 32768 + (wc >> 1) * 16384;
  const char* Bb = lds + 65536 + (b & 1) * 32768 + (wc >> 1) * 16384;
  ds_loadA(Aa, lane, af, 0); ds_loadB(Ba, lane, wc, bf0, 0);
  st.stageA(b, 0); BAR(); mfma_quad(af, bf0, acc, 0, 0); BAR();
  ds_loadB(Ba, lane, wc, bf1, 1);
  st.stageA(b, 1); BAR(); mfma_quad(af, bf1, acc, 0, 1); BAR();
  ds_loadA(Aa, lane, af, 1);
  BAR(); mfma_quad(af, bf0, acc, 1, 0); BAR();
  VMCNT(0); BAR(); mfma_quad(af, bf1, acc, 1, 1); BAR();
  ds_loadA(Ab, lane, af, 0); ds_loadB(Bb, lane, wc, bf0, 0);
  BAR(); mfma_quad(af, bf0, acc, 0, 0); BAR();
  ds_loadB(Bb, lane, wc, bf1, 1);
  BAR(); mfma_quad(af, bf1, acc, 0, 1); BAR();
  ds_loadA(Ab, lane, af, 1);
  BAR(); mfma_quad(af, bf0, acc, 1, 0); BAR();
  mfma_quad(af, bf1, acc, 1, 1);
}

template <class ST>
static __device__ __forceinline__ void prologue(const ST& st) {
  st.stageA(0, 0); st.stageA(0, 1);
  st.stageB(0, 0); st.stageB(0, 1);
  st.stageB(1, 0); st.stageB(1, 1);
  VMCNT(4); BAR();
}

#define STAGE_DECODE(kb)                         \
  int r = (kb) * 8 + (lane >> 3);                \
  int s = (lane & 7) ^ (r & 7);

struct G2Stage {   // A from a_ws (sorted), B from w2b
  const char* a_in; const char* w2b; char* lds; int m0, n0; int w, lane;
  __device__ __forceinline__ void stageA(int t, int half) const {
    char* dst = lds + (t & 1) * 32768 + half * 16384;
    #pragma unroll
    for (int i = 0; i < 2; ++i) {
      int kb = w * 2 + i;
      STAGE_DECODE(kb)
      gload_lds16(a_in + (size_t)(m0 + half * 128 + r) * 2048 + t * 128 + s * 16,
                  dst + kb * 1024);
    }
  }
  __device__ __forceinline__ void stageB(int t, int half) const {
    char* dst = lds + 65536 + (t & 1) * 32768 + half * 16384;
    #pragma unroll
    for (int i = 0; i < 2; ++i) {
      int kb = w * 2 + i;
      STAGE_DECODE(kb)
      gload_lds16(w2b + (size_t)(n0 + half * 128 + r) * 2048 + t * 128 + s * 16,
                  dst + kb * 1024);
    }
  }
};

// --------- GEMM2: out = a @ w2b^T + b2, K bounded by group max width --------
// grid (4, 128); heavy-first: m0 = (127 - by)*256.
// Epilogue: LDS-staged, full 1KB-row float4 stores, scattered by perm.
__global__ __launch_bounds__(512, 2)
void gemm2_kernel8(const unsigned short* __restrict__ a_in,
                   const int* __restrict__ em_sorted,
                   const int* __restrict__ perm,
                   const unsigned short* __restrict__ w2b,
                   const float* __restrict__ b2, float* __restrict__ out) {
  __shared__ __align__(16) char lds[131072];
  const int tid = threadIdx.x, lane = tid & 63, w = tid >> 6;
  const int wr = w >> 2, wc = w & 3;
  const int m0 = (127 - blockIdx.y) * 256, n0 = blockIdx.x * 256;

  int v = em_sorted[m0 + (tid & 255)];
  #pragma unroll
  for (int o = 32; o; o >>= 1) v = max(v, __shfl_xor(v, o));
  int* sred = (int*)lds;
  if (lane == 0) sred[w] = v;
  __syncthreads();
  int maxe = sred[0];
  #pragma unroll
  for (int i = 1; i < 8; ++i) maxe = max(maxe, sred[i]);
  __syncthreads();
  const int J = 1 << maxe;             // kmax/128 iterations

  G2Stage st{(const char*)a_in, (const char*)w2b, lds, m0, n0, w, lane};
  f32x4 acc[8][4] = {};
  bf16x8 af[4][2], bf0[2][2], bf1[2][2];

  prologue(st);
  #pragma clang loop unroll(disable)
  for (int j = 0; j < J - 1; ++j)
    kpair_steady(st, lds, j, lane, wr, wc, af, bf0, bf1, acc);
  kpair_last(st, lds, J - 1, lane, wr, wc, af, bf0, bf1, acc);

  // ---- coalesced epilogue: two 128-row passes through LDS ----
  #pragma unroll
  for (int p = 0; p < 2; ++p) {
    __syncthreads();
    if (wr == p) {
      #pragma unroll
      for (int mf = 0; mf < 8; ++mf)
        #pragma unroll
        for (int nf = 0; nf < 4; ++nf) {
          int col = wc * 64 + nf * 16 + (lane & 15);
          #pragma unroll
          for (int rr = 0; rr < 4; ++rr) {
            int rl = mf * 16 + (lane >> 4) * 4 + rr;
            int byte = (rl * 1024 + col * 4) ^ (((rl >> 2) & 3) << 6);
            *(float*)(lds + byte) = acc[mf][nf][rr];
          }
        }
    }
    __syncthreads();
    float4 bb = *(const float4*)(b2 + n0 + lane * 4);
    #pragma unroll
    for (int i = 0; i < 16; ++i) {
      int rl = i * 8 + w;                     // wave-uniform row 0..127
      int tok = perm[m0 + p * 128 + rl];      // broadcast load
      int byte = (rl * 1024 + lane * 16) ^ (((rl >> 2) & 3) << 6);
      float4 vv = *(const float4*)(lds + byte);
      vv.x += bb.x; vv.y += bb.y; vv.z += bb.z; vv.w += bb.w;
      *(float4*)(out + (size_t)tok * 1024 + n0 + lane * 4) = vv;
    }
  }
}

// ---------------------------------------------------------------------------
extern "C" void kernel_launch(void* const* d_in, const int* in_sizes, int n_in,
                              void* d_out, int out_size, void* d_ws, size_t ws_size,
                              hipStream_t stream) {
  const float* x  = (const float*)d_in[0];
  const int* em   = (const int*)d_in[1];
  const float* w1 = (const float*)d_in[2];
  const float* b1 = (const float*)d_in[3];
  const float* w2 = (const float*)d_in[4];
  const float* b2 = (const float*)d_in[5];
  float* out = (float*)d_out;

  char* ws = (char*)d_ws;
  unsigned short* a_ws = (unsigned short*)ws;                   // 67108864 B
  unsigned short* w1b  = (unsigned short*)(ws + 67108864);      //  4194304 B
  unsigned short* w2b  = (unsigned short*)(ws + 71303168);      //  2097152 B
  unsigned short* xs   = (unsigned short*)(ws + 73400320);      // 67108864 B
  int* perm      = (int*)(ws + 140509184);
  int* em_sorted = (int*)(ws + 140640256);
  int* hist      = (int*)(ws + 140771328);
  int* off       = (int*)(ws + 140775424);

  conv_w_kernel<<<3072, 256, 0, stream>>>(w1, w2, w1b, w2b);
  hist_kernel<<<256, 128, 0, stream>>>(em, hist);
  scan_kernel<<<1, 64, 0, stream>>>(hist, off);
  scatter_kernel<<<256, 128, 0, stream>>>(em, off, perm, em_sorted);
  xconv_kernel<<<16384, 256, 0, stream>>>(x, perm, xs);
  gemm1_sorted_kernel<<<dim3(256, 8), 512, 0, stream>>>(xs, em_sorted, w1b, b1, a_ws);
  gemm2_kernel8<<<dim3(4, 128), 512, 0, stream>>>(a_ws, em_sorted, perm, w2b, b2, out);
}

// Round 14
// 188.093 us; speedup vs baseline: 1.0862x; 1.0862x over previous
//
#include <hip/hip_runtime.h>
#include <stdint.h>

// ---------------------------------------------------------------------------
// NestedSwiGLUMLP: out = (silu(g)*u*mask) @ w2[:, :Hh]^T + b2,  z = x@w1^T + b1
// B=8 S=4096 D=1024 H=2048 Hh=1024 E=4, tokens M=32768
// R14: consolidation to best-measured components.
//   - gemm1: R9's exact 2-phase 128x64 kernel (89us, the best of 6 variants
//     tried this session) + R10's heavy-first m-order.
//   - gemm2: R9's 8-phase 256^2 kernel8 (65us, best of 3 variants).
//   - pre-passes tightened: hist merged into conv_w launch; scan_kernel
//     parallelized (Hillis-Steele over 256 blocks x 4 experts in LDS).
// ws: a(64MB) | w1b(4MB) | w2b(2MB) | xs(64MB) | perm | em_sorted | hist | off
// ---------------------------------------------------------------------------

typedef __attribute__((ext_vector_type(8))) __bf16 bf16x8;
typedef __attribute__((ext_vector_type(4))) float f32x4;

#define MFMA16(a, b, c) __builtin_amdgcn_mfma_f32_16x16x32_bf16(a, b, c, 0, 0, 0)

#define BAR() asm volatile("s_barrier" ::: "memory")
#define VMCNT(n) asm volatile("s_waitcnt vmcnt(" #n ")" ::: "memory")

static __device__ __forceinline__ unsigned short f2bf(float f) {
  union { float f; uint32_t u; } v; v.f = f;
  uint32_t r = v.u + 0x7FFFu + ((v.u >> 16) & 1u);   // RNE
  return (unsigned short)(r >> 16);
}

static __device__ __forceinline__ void gload_lds16(const void* g, void* l) {
  __builtin_amdgcn_global_load_lds(
      (const __attribute__((address_space(1))) void*)g,
      (__attribute__((address_space(3))) void*)l, 16, 0, 0);
}

// ------------- weight cast + histogram (merged, all input-only) -------------
__global__ void prep_kernel(const float* __restrict__ w1,
                            const float* __restrict__ w2,
                            const int* __restrict__ emask,
                            unsigned short* __restrict__ w1b,
                            unsigned short* __restrict__ w2b,
                            int* __restrict__ hist) {
  int bid = blockIdx.x;
  if (bid < 2048) {                                  // w1: 524288 float4s
    int i = bid * 256 + threadIdx.x;
    float4 v = ((const float4*)w1)[i];
    ushort4 o; o.x = f2bf(v.x); o.y = f2bf(v.y); o.z = f2bf(v.z); o.w = f2bf(v.w);
    ((ushort4*)w1b)[i] = o;
  } else if (bid < 3072) {                           // w2[:, :1024]
    int i = (bid - 2048) * 256 + threadIdx.x;
    int d = i >> 8;
    int h4 = (i & 255) * 4;
    float4 v = *(const float4*)(w2 + (size_t)d * 2048 + h4);
    ushort4 o; o.x = f2bf(v.x); o.y = f2bf(v.y); o.z = f2bf(v.z); o.w = f2bf(v.w);
    *(ushort4*)(w2b + (size_t)d * 1024 + h4) = o;
  } else {                                           // hist chunk (128 tokens)
    __shared__ int h[4];
    int tid = threadIdx.x;
    int hb = bid - 3072;                             // 0..255
    if (tid < 4) h[tid] = 0;
    __syncthreads();
    if (tid < 128) atomicAdd(&h[emask[hb * 128 + tid]], 1);
    __syncthreads();
    if (tid < 4) hist[hb * 4 + tid] = h[tid];
  }
}

// ---------------- parallel exclusive scan over 256 chunks x 4 experts -------
__global__ void scan_kernel(const int* __restrict__ hist, int* __restrict__ off) {
  __shared__ int4 sh[256];
  int t = threadIdx.x;                    // 256 threads
  int4 h = ((const int4*)hist)[t];
  int4 val = h;
  sh[t] = val;
  #pragma unroll
  for (int d = 1; d < 256; d <<= 1) {
    __syncthreads();
    int4 add = {0, 0, 0, 0};
    if (t >= d) add = sh[t - d];
    __syncthreads();
    val.x += add.x; val.y += add.y; val.z += add.z; val.w += add.w;
    sh[t] = val;
  }
  __syncthreads();
  int4 tot = sh[255];                     // per-expert totals
  int b1 = tot.x, b2 = tot.x + tot.y, b3 = tot.x + tot.y + tot.z;
  int4 o;
  o.x = val.x - h.x;                      // exclusive within expert 0
  o.y = b1 + (val.y - h.y);
  o.z = b2 + (val.z - h.z);
  o.w = b3 + (val.w - h.w);
  ((int4*)off)[t] = o;
}

__global__ void scatter_kernel(const int* __restrict__ emask,
                               const int* __restrict__ off,
                               int* __restrict__ perm, int* __restrict__ em_sorted) {
  __shared__ int c0[4];
  int tid = threadIdx.x;
  int lane = tid & 63, wid = tid >> 6;
  int t = blockIdx.x * 128 + tid;
  int e = emask[t];
  unsigned long long b0 = __ballot(e == 0);
  unsigned long long b1 = __ballot(e == 1);
  unsigned long long b2 = __ballot(e == 2);
  unsigned long long b3 = __ballot(e == 3);
  if (tid == 0) {
    c0[0] = __popcll(b0); c0[1] = __popcll(b1);
    c0[2] = __popcll(b2); c0[3] = __popcll(b3);
  }
  __syncthreads();
  unsigned long long mine = (e == 0) ? b0 : (e == 1) ? b1 : (e == 2) ? b2 : b3;
  int rank = __popcll(mine & ((1ull << lane) - 1ull));
  if (wid) rank += c0[e];
  int pos = off[blockIdx.x * 4 + e] + rank;
  perm[pos] = t;
  em_sorted[pos] = e;
}

// ------------- x -> bf16, gathered into sorted order ------------------------
__global__ void xconv_kernel(const float* __restrict__ x, const int* __restrict__ perm,
                             unsigned short* __restrict__ xs) {
  int gid = blockIdx.x * 256 + threadIdx.x;
  int s = gid >> 7;
  int seg = gid & 127;
  int tok = perm[s];
  const float* src = x + (size_t)tok * 1024 + seg * 8;
  float4 v0 = *(const float4*)(src);
  float4 v1 = *(const float4*)(src + 4);
  bf16x8 hv;
  hv[0] = (__bf16)v0.x; hv[1] = (__bf16)v0.y; hv[2] = (__bf16)v0.z; hv[3] = (__bf16)v0.w;
  hv[4] = (__bf16)v1.x; hv[5] = (__bf16)v1.y; hv[6] = (__bf16)v1.z; hv[7] = (__bf16)v1.w;
  *(bf16x8*)(xs + (size_t)s * 1024 + seg * 8) = hv;
}

// ---- block-uniform max expert of sorted rows [m0, m0+128) ------------------
static __device__ __forceinline__ int block_max_e(const int* em_sorted, int m0,
                                                  int tid, int* sred) {
  int v = 0;
  if (tid < 128) v = em_sorted[m0 + tid];
  #pragma unroll
  for (int o = 32; o; o >>= 1) v = max(v, __shfl_xor(v, o));
  if ((tid & 63) == 0) sred[tid >> 6] = v;
  __syncthreads();
  return max(sred[0], sred[1]);
}

// --------- GEMM1 (R9 exact, 2-phase 128x64): z tile + swiglu epilogue -------
// grid (256, 16): x -> m-group (reversed: heavy first; XCD = x%8), y = 64-col
__global__ __launch_bounds__(256, 4)
void gemm1_sorted_kernel(const unsigned short* __restrict__ xs,
                         const int* __restrict__ em_sorted,
                         const unsigned short* __restrict__ w1b,
                         const float* __restrict__ b1,
                         unsigned short* __restrict__ a_out) {
  __shared__ __align__(16) char lds[32768];
  __shared__ int sred[4];
  char* AS = lds;             // 128 rows x 128B, swizzled
  char* BS = lds + 16384;     // rows 0..63 = gate n0+r, 64..127 = up 1024+n0+r

  const int tid = threadIdx.x;
  const int lane = tid & 63;
  const int w = tid >> 6;
  const int wm = w & 1;
  const int wn = w >> 1;
  const int m0 = (255 - blockIdx.x) * 128;     // heavy groups dispatch first
  const int n0 = blockIdx.y * 64;

  int maxe = block_max_e(em_sorted, m0, tid, sred);
  if (n0 >= (128 << maxe)) return;      // whole tile inactive for this group

  f32x4 accg[4][2] = {};
  f32x4 accu[4][2] = {};

  for (int k0 = 0; k0 < 1024; k0 += 64) {
    #pragma unroll
    for (int i = 0; i < 4; ++i) {
      int c = (w * 4 + i) * 64 + lane;        // 16B chunk id in [0,1024)
      int p = c * 16;
      int r = p >> 7;                         // 0..127
      int kb16 = ((p >> 4) & 7) ^ (r & 7);
      gload_lds16((const char*)xs + (((size_t)(m0 + r) * 1024 + k0) * 2) + kb16 * 16,
                  AS + (w * 4 + i) * 1024);
      int h = (r < 64) ? (n0 + r) : (1024 + n0 + (r - 64));
      gload_lds16((const char*)w1b + (((size_t)h * 1024 + k0) * 2) + kb16 * 16,
                  BS + (w * 4 + i) * 1024);
    }
    __syncthreads();
    #pragma unroll
    for (int kk = 0; kk < 2; ++kk) {
      const int kbyte = kk * 64 + (lane >> 4) * 16;
      bf16x8 af[4], bg[2], bu[2];
      #pragma unroll
      for (int m = 0; m < 4; ++m) {
        int r = wm * 64 + m * 16 + (lane & 15);
        int o = (r * 128 + kbyte) ^ ((r & 7) << 4);
        af[m] = *(const bf16x8*)(AS + o);
      }
      #pragma unroll
      for (int n = 0; n < 2; ++n) {
        int r = wn * 32 + n * 16 + (lane & 15);
        int o = (r * 128 + kbyte) ^ ((r & 7) << 4);
        bg[n] = *(const bf16x8*)(BS + o);
        bu[n] = *(const bf16x8*)(BS + 8192 + o);
      }
      #pragma unroll
      for (int m = 0; m < 4; ++m)
        #pragma unroll
        for (int n = 0; n < 2; ++n) {
          accg[m][n] = MFMA16(af[m], bg[n], accg[m][n]);
          accu[m][n] = MFMA16(af[m], bu[n], accu[m][n]);
        }
    }
    __syncthreads();
  }
  #pragma unroll
  for (int m = 0; m < 4; ++m) {
    int rbase = m0 + wm * 64 + m * 16 + (lane >> 4) * 4;
    int act[4];
    #pragma unroll
    for (int r = 0; r < 4; ++r) act[r] = 128 << em_sorted[rbase + r];
    #pragma unroll
    for (int n = 0; n < 2; ++n) {
      int col = n0 + wn * 32 + n * 16 + (lane & 15);
      float b1g = b1[col], b1u = b1[col + 1024];
      #pragma unroll
      for (int r = 0; r < 4; ++r) {
        float g = accg[m][n][r] + b1g;
        float u = accu[m][n][r] + b1u;
        float s = g / (1.f + __expf(-g));
        float val = (col < act[r]) ? (s * u) : 0.f;
        a_out[(size_t)(rbase + r) * 1024 + col] = f2bf(val);
      }
    }
  }
}

// ======================= 8-phase 256x256 GEMM machinery (gemm2) =============
static __device__ __forceinline__ void ds_loadA(const char* Abase, int lane,
                                                bf16x8 (&af)[4][2], int mh) {
  #pragma unroll
  for (int mf = 0; mf < 4; ++mf)
    #pragma unroll
    for (int kk = 0; kk < 2; ++kk) {
      int r = mh * 64 + mf * 16 + (lane & 15);
      int o = (r * 128 + kk * 64 + ((lane >> 4) * 16)) ^ ((r & 7) << 4);
      af[mf][kk] = *(const bf16x8*)(Abase + o);
    }
}

static __device__ __forceinline__ void ds_loadB(const char* Bbase, int lane, int wc,
                                                bf16x8 (&bf)[2][2], int nh) {
  #pragma unroll
  for (int nl = 0; nl < 2; ++nl)
    #pragma unroll
    for (int kk = 0; kk < 2; ++kk) {
      int n = nh * 2 + nl;
      int r = (wc & 1) * 64 + n * 16 + (lane & 15);
      int o = (r * 128 + kk * 64 + ((lane >> 4) * 16)) ^ ((r & 7) << 4);
      bf[nl][kk] = *(const bf16x8*)(Bbase + o);
    }
}

static __device__ __forceinline__ void mfma_quad(bf16x8 (&af)[4][2], bf16x8 (&bf)[2][2],
                                                 f32x4 (&acc)[8][4], int mh, int nh) {
  __builtin_amdgcn_s_setprio(1);
  #pragma unroll
  for (int mf = 0; mf < 4; ++mf)
    #pragma unroll
    for (int nl = 0; nl < 2; ++nl)
      #pragma unroll
      for (int kk = 0; kk < 2; ++kk)
        acc[mh * 4 + mf][nh * 2 + nl] =
            MFMA16(af[mf][kk], bf[nl][kk], acc[mh * 4 + mf][nh * 2 + nl]);
  __builtin_amdgcn_s_setprio(0);
}

template <class ST>
static __device__ __forceinline__ void kpair_steady(const ST& st, char* lds, int j,
    int lane, int wr, int wc, bf16x8 (&af)[4][2], bf16x8 (&bf0)[2][2],
    bf16x8 (&bf1)[2][2], f32x4 (&acc)[8][4]) {
  const int a = 2 * j, b = 2 * j + 1;
  const char* Aa = lds + (a & 1) * 32768 + wr * 16384;
  const char* Ab = lds + (b & 1) * 32768 + wr * 16384;
  const char* Ba = lds + 65536 + (a & 1) * 32768 + (wc >> 1) * 16384;
  const char* Bb = lds + 65536 + (b & 1) * 32768 + (wc >> 1) * 16384;
  ds_loadA(Aa, lane, af, 0); ds_loadB(Ba, lane, wc, bf0, 0);
  st.stageA(b, 0);            BAR(); mfma_quad(af, bf0, acc, 0, 0); BAR();
  ds_loadB(Ba, lane, wc, bf1, 1);
  st.stageA(b, 1);            BAR(); mfma_quad(af, bf1, acc, 0, 1); BAR();
  ds_loadA(Aa, lane, af, 1);
  st.stageB(a + 2, 0);        BAR(); mfma_quad(af, bf0, acc, 1, 0); BAR();
  st.stageB(a + 2, 1); VMCNT(4); BAR(); mfma_quad(af, bf1, acc, 1, 1); BAR();
  ds_loadA(Ab, lane, af, 0); ds_loadB(Bb, lane, wc, bf0, 0);
  st.stageA(a + 2, 0);        BAR(); mfma_quad(af, bf0, acc, 0, 0); BAR();
  ds_loadB(Bb, lane, wc, bf1, 1);
  st.stageA(a + 2, 1);        BAR(); mfma_quad(af, bf1, acc, 0, 1); BAR();
  ds_loadA(Ab, lane, af, 1);
  st.stageB(b + 2, 0);        BAR(); mfma_quad(af, bf0, acc, 1, 0); BAR();
  st.stageB(b + 2, 1); VMCNT(4); BAR(); mfma_quad(af, bf1, acc, 1, 1); BAR();
}

template <class ST>
static __device__ __forceinline__ void kpair_last(const ST& st, char* lds, int j,
    int lane, int wr, int wc, bf16x8 (&af)[4][2], bf16x8 (&bf0)[2][2],
    bf16x8 (&bf1)[2][2], f32x4 (&acc)[8][4]) {
  const int a = 2 * j, b = 2 * j + 1;
  const char* Aa = lds + (a & 1) * 32768 + wr * 16384;
  const char* Ab = lds + (b & 1) * 32768 + wr * 16384;
  const char* Ba = lds + 65536 + (a & 1) * 32768 + (wc >> 1) * 16384;
  const char* Bb = lds + 65536 + (b & 1) * 32768 + (wc >> 1) * 16384;
  ds_loadA(Aa, lane, af, 0); ds_loadB(Ba, lane, wc, bf0, 0);
  st.stageA(b, 0); BAR(); mfma_quad(af, bf0, acc, 0, 0); BAR();
  ds_loadB(Ba, lane, wc, bf1, 1);
  st.stageA(b, 1); BAR(); mfma_quad(af, bf1, acc, 0, 1); BAR();
  ds_loadA(Aa, lane, af, 1);
  BAR(); mfma_quad(af, bf0, acc, 1, 0); BAR();
  VMCNT(0); BAR(); mfma_quad(af, bf1, acc, 1, 1); BAR();
  ds_loadA(Ab, lane, af, 0); ds_loadB(Bb, lane, wc, bf0, 0);
  BAR(); mfma_quad(af, bf0, acc, 0, 0); BAR();
  ds_loadB(Bb, lane, wc, bf1, 1);
  BAR(); mfma_quad(af, bf1, acc, 0, 1); BAR();
  ds_loadA(Ab, lane, af, 1);
  BAR(); mfma_quad(af, bf0, acc, 1, 0); BAR();
  mfma_quad(af, bf1, acc, 1, 1);
}

template <class ST>
static __device__ __forceinline__ void prologue(const ST& st) {
  st.stageA(0, 0); st.stageA(0, 1);
  st.stageB(0, 0); st.stageB(0, 1);
  st.stageB(1, 0); st.stageB(1, 1);
  VMCNT(4); BAR();
}

#define STAGE_DECODE(kb)                         \
  int r = (kb) * 8 + (lane >> 3);                \
  int s = (lane & 7) ^ (r & 7);

struct G2Stage {   // A from a_ws (sorted), B from w2b
  const char* a_in; const char* w2b; char* lds; int m0, n0; int w, lane;
  __device__ __forceinline__ void stageA(int t, int half) const {
    char* dst = lds + (t & 1) * 32768 + half * 16384;
    #pragma unroll
    for (int i = 0; i < 2; ++i) {
      int kb = w * 2 + i;
      STAGE_DECODE(kb)
      gload_lds16(a_in + (size_t)(m0 + half * 128 + r) * 2048 + t * 128 + s * 16,
                  dst + kb * 1024);
    }
  }
  __device__ __forceinline__ void stageB(int t, int half) const {
    char* dst = lds + 65536 + (t & 1) * 32768 + half * 16384;
    #pragma unroll
    for (int i = 0; i < 2; ++i) {
      int kb = w * 2 + i;
      STAGE_DECODE(kb)
      gload_lds16(w2b + (size_t)(n0 + half * 128 + r) * 2048 + t * 128 + s * 16,
                  dst + kb * 1024);
    }
  }
};

// --------- GEMM2: out = a @ w2b^T + b2, K bounded by group max width --------
// grid (4, 128); heavy-first: m0 = (127 - by)*256.
// Epilogue: LDS-staged, full 1KB-row float4 stores, scattered by perm.
__global__ __launch_bounds__(512, 2)
void gemm2_kernel8(const unsigned short* __restrict__ a_in,
                   const int* __restrict__ em_sorted,
                   const int* __restrict__ perm,
                   const unsigned short* __restrict__ w2b,
                   const float* __restrict__ b2, float* __restrict__ out) {
  __shared__ __align__(16) char lds[131072];
  const int tid = threadIdx.x, lane = tid & 63, w = tid >> 6;
  const int wr = w >> 2, wc = w & 3;
  const int m0 = (127 - blockIdx.y) * 256, n0 = blockIdx.x * 256;

  int v = em_sorted[m0 + (tid & 255)];
  #pragma unroll
  for (int o = 32; o; o >>= 1) v = max(v, __shfl_xor(v, o));
  int* sred = (int*)lds;
  if (lane == 0) sred[w] = v;
  __syncthreads();
  int maxe = sred[0];
  #pragma unroll
  for (int i = 1; i < 8; ++i) maxe = max(maxe, sred[i]);
  __syncthreads();
  const int J = 1 << maxe;             // kmax/128 iterations

  G2Stage st{(const char*)a_in, (const char*)w2b, lds, m0, n0, w, lane};
  f32x4 acc[8][4] = {};
  bf16x8 af[4][2], bf0[2][2], bf1[2][2];

  prologue(st);
  #pragma clang loop unroll(disable)
  for (int j = 0; j < J - 1; ++j)
    kpair_steady(st, lds, j, lane, wr, wc, af, bf0, bf1, acc);
  kpair_last(st, lds, J - 1, lane, wr, wc, af, bf0, bf1, acc);

  // ---- coalesced epilogue: two 128-row passes through LDS ----
  #pragma unroll
  for (int p = 0; p < 2; ++p) {
    __syncthreads();
    if (wr == p) {
      #pragma unroll
      for (int mf = 0; mf < 8; ++mf)
        #pragma unroll
        for (int nf = 0; nf < 4; ++nf) {
          int col = wc * 64 + nf * 16 + (lane & 15);
          #pragma unroll
          for (int rr = 0; rr < 4; ++rr) {
            int rl = mf * 16 + (lane >> 4) * 4 + rr;
            int byte = (rl * 1024 + col * 4) ^ (((rl >> 2) & 3) << 6);
            *(float*)(lds + byte) = acc[mf][nf][rr];
          }
        }
    }
    __syncthreads();
    float4 bb = *(const float4*)(b2 + n0 + lane * 4);
    #pragma unroll
    for (int i = 0; i < 16; ++i) {
      int rl = i * 8 + w;                     // wave-uniform row 0..127
      int tok = perm[m0 + p * 128 + rl];      // broadcast load
      int byte = (rl * 1024 + lane * 16) ^ (((rl >> 2) & 3) << 6);
      float4 vv = *(const float4*)(lds + byte);
      vv.x += bb.x; vv.y += bb.y; vv.z += bb.z; vv.w += bb.w;
      *(float4*)(out + (size_t)tok * 1024 + n0 + lane * 4) = vv;
    }
  }
}

// ---------------------------------------------------------------------------
extern "C" void kernel_launch(void* const* d_in, const int* in_sizes, int n_in,
                              void* d_out, int out_size, void* d_ws, size_t ws_size,
                              hipStream_t stream) {
  const float* x  = (const float*)d_in[0];
  const int* em   = (const int*)d_in[1];
  const float* w1 = (const float*)d_in[2];
  const float* b1 = (const float*)d_in[3];
  const float* w2 = (const float*)d_in[4];
  const float* b2 = (const float*)d_in[5];
  float* out = (float*)d_out;

  char* ws = (char*)d_ws;
  unsigned short* a_ws = (unsigned short*)ws;                   // 67108864 B
  unsigned short* w1b  = (unsigned short*)(ws + 67108864);      //  4194304 B
  unsigned short* w2b  = (unsigned short*)(ws + 71303168);      //  2097152 B
  unsigned short* xs   = (unsigned short*)(ws + 73400320);      // 67108864 B
  int* perm      = (int*)(ws + 140509184);
  int* em_sorted = (int*)(ws + 140640256);
  int* hist      = (int*)(ws + 140771328);
  int* off       = (int*)(ws + 140775424);

  prep_kernel<<<3328, 256, 0, stream>>>(w1, w2, em, w1b, w2b, hist);
  scan_kernel<<<1, 256, 0, stream>>>(hist, off);
  scatter_kernel<<<256, 128, 0, stream>>>(em, off, perm, em_sorted);
  xconv_kernel<<<16384, 256, 0, stream>>>(x, perm, xs);
  gemm1_sorted_kernel<<<dim3(256, 16), 256, 0, stream>>>(xs, em_sorted, w1b, b1, a_ws);
  gemm2_kernel8<<<dim3(4, 128), 512, 0, stream>>>(a_ws, em_sorted, perm, w2b, b2, out);
}